// Round 11
// baseline (224.084 us; speedup 1.0000x reference)
//
#include <hip/hip_runtime.h>
#include <hip/hip_bf16.h>

// Sizes: S=128, B=64, N=64, K=16, P=48, M=32
// Outputs: A [S,B,64,64] (C=4096), Bo [S,B,64,32] (C=2048), Cc [S,B,48,64] (C=3072)
#define SB 8192   // S*B

typedef float f4 __attribute__((ext_vector_type(4)));  // clang-native vec4

__device__ __forceinline__ float fsig(float x) {
    return __builtin_amdgcn_rcpf(1.f + __expf(-x));
}
__device__ __forceinline__ float ftanh(float x) {
    return fmaf(-2.f, __builtin_amdgcn_rcpf(1.f + __expf(2.f * x)), 1.f);
}

// ---------------------------------------------------------------------------
// Kernel 1 (identical to R10): gate-interleaved input projection.
// ---------------------------------------------------------------------------
__global__ __launch_bounds__(256) void xgate_kernel(
    const float* __restrict__ x,    // [8192][64]
    const float* __restrict__ Wih,  // [64][64]
    const float* __restrict__ bih,  // [64]
    const float* __restrict__ bhh,  // [64]
    float* __restrict__ xg)         // [8192][16][4] gate-interleaved
{
    __shared__ float xs[4][64];
    const int tid = threadIdx.x;
    const int rl  = tid >> 6;
    const int g   = tid & 63;           // weight row: g = q*16 + t
    const size_t rowBase = (size_t)blockIdx.x * 4;

    xs[rl][g] = x[rowBase * 64 + tid];
    __syncthreads();

    const float* xr = xs[rl];
    float acc = bih[g] + bhh[g];
#pragma unroll
    for (int n = 0; n < 64; n += 4) {
        f4 wv = *reinterpret_cast<const f4*>(&Wih[g * 64 + n]);
        acc = fmaf(xr[n + 0], wv.x, acc);
        acc = fmaf(xr[n + 1], wv.y, acc);
        acc = fmaf(xr[n + 2], wv.z, acc);
        acc = fmaf(xr[n + 3], wv.w, acc);
    }
    xg[(rowBase + rl) * 64 + (g & 15) * 4 + (g >> 4)] = acc;
}

// ---------------------------------------------------------------------------
// Kernel 2 (identical to R10): producer/consumer staged LSTM scan.
// Bounded ~10 us by construction (LDS-fed serial chain).
// ---------------------------------------------------------------------------
__global__ __launch_bounds__(256) void lstm_scan_staged_kernel(
    const float* __restrict__ xg,   // [S][B][16][4]  (f4 idx: row*16 + t)
    const float* __restrict__ Whh,  // [64][16]
    float* __restrict__ w)          // [S][B][16]
{
    __shared__ f4 buf[2][1024];
    const int tid  = threadIdx.x;
    const int wave = tid >> 6;
    const int b0   = blockIdx.x * 4;
    const f4* xgf4 = reinterpret_cast<const f4*>(xg);

    float wi[16], wf[16], wg[16], wo[16];
    const int t  = tid & 15;
    const int bb = (tid >> 4) & 3;
    if (wave == 0) {
#pragma unroll
        for (int k = 0; k < 16; ++k) {
            wi[k] = Whh[(0 * 16 + t) * 16 + k];
            wf[k] = Whh[(1 * 16 + t) * 16 + k];
            wg[k] = Whh[(2 * 16 + t) * 16 + k];
            wo[k] = Whh[(3 * 16 + t) * 16 + k];
        }
    } else {
        const int lane = tid - 64;                 // 0..191
        for (int j = lane; j < 1024; j += 192)
            buf[0][j] = xgf4[(size_t)(j >> 6) * 1024 + b0 * 16 + (j & 63)];
    }
    __syncthreads();

    float h = 0.f, c = 0.f;
    for (int chunk = 0; chunk < 8; ++chunk) {
        if (wave == 0) {
            const f4* xb = &buf[chunk & 1][bb * 16 + t];
#pragma unroll
            for (int u = 0; u < 16; ++u) {
                f4 xv = xb[u * 64];
                float ai = xv.x, af = xv.y, ag = xv.z, ao = xv.w;
#pragma unroll
                for (int k = 0; k < 16; ++k) {
                    float hk = __shfl(h, k, 16);
                    ai = fmaf(hk, wi[k], ai);
                    af = fmaf(hk, wf[k], af);
                    ag = fmaf(hk, wg[k], ag);
                    ao = fmaf(hk, wo[k], ao);
                }
                float ig = fsig(ai), fg = fsig(af), og = fsig(ao);
                float gt = ftanh(ag);
                c = fg * c + ig * gt;
                h = og * ftanh(c);
                w[((size_t)(chunk * 16 + u) * 64 + (b0 + bb)) * 16 + t] = h;
            }
        } else if (chunk + 1 < 8) {
            const int lane = tid - 64;
            f4* dst = buf[(chunk + 1) & 1];
            const size_t base = (size_t)(chunk + 1) * 16 * 1024 + b0 * 16;
            for (int j = lane; j < 1024; j += 192)
                dst[j] = xgf4[base + (size_t)(j >> 6) * 1024 + (j & 63)];
        }
        __syncthreads();
    }
}

// ---------------------------------------------------------------------------
// Kernel 3 (identical to R10): out[row][i] = sum_k w[row][k]*M[k][i].
// DIAGNOSTIC THIS ROUND: launched 3x back-to-back (idempotent) to measure
// its duration via the total: wsum = (total - 123.6)/2.
// ---------------------------------------------------------------------------
__global__ __launch_bounds__(256) void wsum_all_kernel(
    const float* __restrict__ w,   // [8192][16]
    const float* __restrict__ As, const float* __restrict__ Bs,
    const float* __restrict__ Cs,
    float* __restrict__ outA, float* __restrict__ outB, float* __restrict__ outC)
{
    const int tid = threadIdx.x;
    const int bid = blockIdx.x;

    const float* M; float* o; int C, local, colTiles;
    if (bid < 1024)      { M = As; o = outA; C = 4096; local = bid;        colTiles = 4; }
    else if (bid < 1536) { M = Bs; o = outB; C = 2048; local = bid - 1024; colTiles = 2; }
    else                 { M = Cs; o = outC; C = 3072; local = bid - 1536; colTiles = 3; }

    const int colTile  = local % colTiles;
    const int rowStart = (local / colTiles) * 32;
    const int i4 = colTile * 1024 + tid * 4;

    f4 m[16];
#pragma unroll
    for (int k = 0; k < 16; ++k)
        m[k] = *reinterpret_cast<const f4*>(&M[(size_t)k * C + i4]);

    const float* wp = w + (size_t)rowStart * 16;   // wave-uniform
    float* op = o + (size_t)rowStart * C + i4;

#pragma unroll 2
    for (int r = 0; r < 32; ++r) {
        f4 acc = (f4)0.f;
#pragma unroll
        for (int k = 0; k < 16; ++k)
            acc += wp[r * 16 + k] * m[k];          // uniform -> s_load
        *reinterpret_cast<f4*>(op) = acc;
        op += C;
    }
}

// ---------------------------------------------------------------------------
extern "C" void kernel_launch(void* const* d_in, const int* in_sizes, int n_in,
                              void* d_out, int out_size, void* d_ws, size_t ws_size,
                              hipStream_t stream) {
    const float* state = (const float*)d_in[0];
    const float* W_ih  = (const float*)d_in[1];
    const float* W_hh  = (const float*)d_in[2];
    const float* b_ih  = (const float*)d_in[3];
    const float* b_hh  = (const float*)d_in[4];
    const float* As    = (const float*)d_in[5];
    const float* Bs    = (const float*)d_in[6];
    const float* Cs    = (const float*)d_in[7];
    float* out = (float*)d_out;

    float* xg = (float*)d_ws;            // 8192*64 floats
    float* w  = xg + (size_t)SB * 64;    // 8192*16 floats

    xgate_kernel<<<SB / 4, 256, 0, stream>>>(state, W_ih, b_ih, b_hh, xg);
    lstm_scan_staged_kernel<<<16, 256, 0, stream>>>(xg, W_hh, w);

    float* outA = out;
    float* outB = out + (size_t)SB * 4096;
    float* outC = out + (size_t)SB * 4096 + (size_t)SB * 2048;

    // Diagnostic: 3 identical launches (idempotent). total = base + 3*wsum.
    wsum_all_kernel<<<2304, 256, 0, stream>>>(w, As, Bs, Cs, outA, outB, outC);
    wsum_all_kernel<<<2304, 256, 0, stream>>>(w, As, Bs, Cs, outA, outB, outC);
    wsum_all_kernel<<<2304, 256, 0, stream>>>(w, As, Bs, Cs, outA, outB, outC);
}

// Round 14
// 109.651 us; speedup vs baseline: 2.0436x; 2.0436x over previous
//
#include <hip/hip_runtime.h>
#include <hip/hip_bf16.h>

// Sizes: S=128, B=64, N=64, K=16, P=48, M=32
// Outputs: A [S,B,64,64] (C=4096), Bo [S,B,64,32] (C=2048), Cc [S,B,48,64] (C=3072)
#define SB 8192   // S*B
#define NCONS 496 // consumer blocks in fused kernel

typedef float f4 __attribute__((ext_vector_type(4)));  // clang-native vec4

__device__ __forceinline__ float fsig(float x) {
    return __builtin_amdgcn_rcpf(1.f + __expf(-x));
}
__device__ __forceinline__ float ftanh(float x) {
    return fmaf(-2.f, __builtin_amdgcn_rcpf(1.f + __expf(2.f * x)), 1.f);
}

// ---------------------------------------------------------------------------
// Kernel 1: gate-interleaved input projection (R10-identical) + zero flags.
// ---------------------------------------------------------------------------
__global__ __launch_bounds__(256) void xgate_kernel(
    const float* __restrict__ x,    // [8192][64]
    const float* __restrict__ Wih,  // [64][64]
    const float* __restrict__ bih,
    const float* __restrict__ bhh,
    float* __restrict__ xg,         // [8192][16][4] gate-interleaved
    unsigned int* __restrict__ flags)
{
    __shared__ float xs[4][64];
    const int tid = threadIdx.x;
    if (blockIdx.x == 0 && tid < 2) flags[tid] = 0u;

    const int rl  = tid >> 6;
    const int g   = tid & 63;           // weight row: g = q*16 + t
    const size_t rowBase = (size_t)blockIdx.x * 4;

    xs[rl][g] = x[rowBase * 64 + tid];
    __syncthreads();

    const float* xr = xs[rl];
    float acc = bih[g] + bhh[g];
#pragma unroll
    for (int n = 0; n < 64; n += 4) {
        f4 wv = *reinterpret_cast<const f4*>(&Wih[g * 64 + n]);
        acc = fmaf(xr[n + 0], wv.x, acc);
        acc = fmaf(xr[n + 1], wv.y, acc);
        acc = fmaf(xr[n + 2], wv.z, acc);
        acc = fmaf(xr[n + 3], wv.w, acc);
    }
    xg[(rowBase + rl) * 64 + (g & 15) * 4 + (g >> 4)] = acc;
}

// ---------------------------------------------------------------------------
// Kernel 2 (fused, ordinary launch): blocks 0-15 scan, blocks 16-511 consume.
// Scan: R6-exact (wave 0, LDS h-broadcast, 1-step xg prefetch); releases
// flag[0] after s=63, flag[1] after s=127 (RELEASE fences the wave's stores).
// Consumers: tiles in s-order; RELAXED poll + s_sleep, one ACQUIRE on success;
// w staged to LDS via VECTOR loads (scalar K$ is not coherence-safe here).
// Deadlock-free at any occupancy: scan blocks dispatch first, never wait.
// ---------------------------------------------------------------------------
__global__ __launch_bounds__(256, 2) void fused_kernel(
    const float* __restrict__ xg,   // [S][B][16][4]
    const float* __restrict__ Whh,  // [64][16]
    float* __restrict__ w,          // [S][B][16]
    unsigned int* __restrict__ flags,
    const float* __restrict__ As, const float* __restrict__ Bs,
    const float* __restrict__ Cs,
    float* __restrict__ outA, float* __restrict__ outB, float* __restrict__ outC)
{
    __shared__ f4 ws[128];                  // consumer w-tile stage (32 rows)
    __shared__ alignas(16) float hs[64];    // scan h broadcast
    const int tid = threadIdx.x;
    const int bid = blockIdx.x;

    if (bid < 16) {
        // ---------------- producer: LSTM scan (wave 0 only) ----------------
        if (tid >= 64) return;
        const int t  = tid & 15;
        const int b4 = tid >> 4;
        const int b  = bid * 4 + b4;

        float wi[16], wf[16], wg[16], wo[16];
#pragma unroll
        for (int k = 0; k < 16; ++k) {
            wi[k] = Whh[(0 * 16 + t) * 16 + k];
            wf[k] = Whh[(1 * 16 + t) * 16 + k];
            wg[k] = Whh[(2 * 16 + t) * 16 + k];
            wo[k] = Whh[(3 * 16 + t) * 16 + k];
        }

        const f4* xp = reinterpret_cast<const f4*>(xg) + b * 16 + t;
        f4 xv = xp[0];
        float h = 0.f, c = 0.f;
        for (int s = 0; s < 128; ++s) {
            f4 nx = (s < 127) ? xp[(size_t)(s + 1) * 1024] : (f4)0.f;

            hs[tid] = h;                    // wave-local LDS, in-order pipe
            asm volatile("s_waitcnt lgkmcnt(0)" ::: "memory");
            union { f4 v[4]; float f[16]; } hh;
            hh.v[0] = *reinterpret_cast<const f4*>(&hs[b4 * 16 + 0]);
            hh.v[1] = *reinterpret_cast<const f4*>(&hs[b4 * 16 + 4]);
            hh.v[2] = *reinterpret_cast<const f4*>(&hs[b4 * 16 + 8]);
            hh.v[3] = *reinterpret_cast<const f4*>(&hs[b4 * 16 + 12]);

            float ai = xv.x, af = xv.y, ag = xv.z, ao = xv.w;
#pragma unroll
            for (int k = 0; k < 16; ++k) {
                float hk = hh.f[k];
                ai = fmaf(hk, wi[k], ai);
                af = fmaf(hk, wf[k], af);
                ag = fmaf(hk, wg[k], ag);
                ao = fmaf(hk, wo[k], ao);
            }
            float ig = fsig(ai), fg = fsig(af), og = fsig(ao);
            float gt = ftanh(ag);
            c = fg * c + ig * gt;
            h = og * ftanh(c);
            w[((size_t)s * 64 + b) * 16 + t] = h;
            xv = nx;

            if (s == 63 && tid == 0)
                __hip_atomic_fetch_add(&flags[0], 1u, __ATOMIC_RELEASE,
                                       __HIP_MEMORY_SCOPE_AGENT);
        }
        if (tid == 0)
            __hip_atomic_fetch_add(&flags[1], 1u, __ATOMIC_RELEASE,
                                   __HIP_MEMORY_SCOPE_AGENT);
        return;
    }

    // ---------------- consumers: weighted-sum tiles in s-order --------------
    // tile T in [0,2304): s = T/18; r = T%18 -> ct = r>>1 (0-8), bhalf = r&1.
    const int j = bid - 16;
    int have = -1;
    for (int T = j; T < 2304; T += NCONS) {
        const int s    = T / 18;
        const int r    = T % 18;
        const int need = (s < 64) ? 0 : 1;

        if (need != have) {
            if (tid == 0) {
                while (__hip_atomic_load(&flags[need], __ATOMIC_RELAXED,
                                         __HIP_MEMORY_SCOPE_AGENT) < 16u)
                    __builtin_amdgcn_s_sleep(64);   // ~1.7 us between polls
                (void)__hip_atomic_load(&flags[need], __ATOMIC_ACQUIRE,
                                        __HIP_MEMORY_SCOPE_AGENT);
            }
            __syncthreads();                        // all threads see fresh w
            have = need;
        }

        const int ct = r >> 1;
        const int rowStart = s * 64 + (r & 1) * 32;

        const float* M; float* o; int C, cto;
        if (ct < 4)      { M = As; o = outA; C = 4096; cto = ct; }
        else if (ct < 6) { M = Bs; o = outB; C = 2048; cto = ct - 4; }
        else             { M = Cs; o = outC; C = 3072; cto = ct - 6; }
        const int i4 = cto * 1024 + tid * 4;

        // stage 32 rows of w (512 floats = 128 f4) via VECTOR loads
        if (tid < 128)
            ws[tid] = reinterpret_cast<const f4*>(w)[rowStart * 4 + tid];

        // matrix slice into registers (L2-resident)
        f4 m[16];
#pragma unroll
        for (int q = 0; q < 16; ++q)
            m[q] = *reinterpret_cast<const f4*>(&M[(size_t)q * C + i4]);

        __syncthreads();                            // ws ready

        float* op = o + (size_t)rowStart * C + i4;
#pragma unroll 2
        for (int r2 = 0; r2 < 32; ++r2) {
            f4 w0 = ws[r2 * 4 + 0];                 // ds_read_b128 broadcast
            f4 w1 = ws[r2 * 4 + 1];
            f4 w2 = ws[r2 * 4 + 2];
            f4 w3 = ws[r2 * 4 + 3];
            f4 acc = (f4)0.f;
#pragma unroll
            for (int q = 0; q < 4; ++q) acc += w0[q] * m[q + 0];
#pragma unroll
            for (int q = 0; q < 4; ++q) acc += w1[q] * m[q + 4];
#pragma unroll
            for (int q = 0; q < 4; ++q) acc += w2[q] * m[q + 8];
#pragma unroll
            for (int q = 0; q < 4; ++q) acc += w3[q] * m[q + 12];
            *reinterpret_cast<f4*>(op) = acc;
            op += C;
        }
        __syncthreads();                            // protect ws before restage
    }
}

// ---------------------------------------------------------------------------
extern "C" void kernel_launch(void* const* d_in, const int* in_sizes, int n_in,
                              void* d_out, int out_size, void* d_ws, size_t ws_size,
                              hipStream_t stream) {
    const float* state = (const float*)d_in[0];
    const float* W_ih  = (const float*)d_in[1];
    const float* W_hh  = (const float*)d_in[2];
    const float* b_ih  = (const float*)d_in[3];
    const float* b_hh  = (const float*)d_in[4];
    const float* As    = (const float*)d_in[5];
    const float* Bs    = (const float*)d_in[6];
    const float* Cs    = (const float*)d_in[7];
    float* out = (float*)d_out;

    float* xg = (float*)d_ws;                     // 8192*64 floats
    float* w  = xg + (size_t)SB * 64;             // 8192*16 floats
    unsigned int* flags = (unsigned int*)(w + (size_t)SB * 16);   // 2 flags

    float* outA = out;
    float* outB = out + (size_t)SB * 4096;
    float* outC = out + (size_t)SB * 4096 + (size_t)SB * 2048;

    xgate_kernel<<<SB / 4, 256, 0, stream>>>(state, W_ih, b_ih, b_hh, xg, flags);
    fused_kernel<<<16 + NCONS, 256, 0, stream>>>(xg, W_hh, w, flags,
                                                 As, Bs, Cs, outA, outB, outC);
}